// Round 1
// baseline (787.460 us; speedup 1.0000x reference)
//
#include <hip/hip_runtime.h>

// Sizes fixed by the problem: B=1, L=768, D=128, H=8, DH=16, N=6 layers.
#define L_SEQ 768
#define D_MOD 128
#define P_SZ  (L_SEQ * D_MOD)   // 98304

// ---------------------------------------------------------------------------
// C[768 x Nd] = A[768 x 128] @ B[Nd x 128]^T + bias[Nd] (+ X[768 x Nd] if X)
// Torch Linear convention. Tile 32x32, full K=128 staged in LDS.
// ---------------------------------------------------------------------------
__global__ __launch_bounds__(256) void gemm_bt(const float* __restrict__ A,
    const float* __restrict__ B, const float* __restrict__ bias,
    const float* __restrict__ X, float* __restrict__ C, int Nd)
{
    __shared__ float As[32][129];
    __shared__ float Bs[32][129];
    const int r0 = blockIdx.x * 32;
    const int n0 = blockIdx.y * 32;
    const int tid = threadIdx.x;
#pragma unroll
    for (int t = 0; t < 16; ++t) {
        int idx = tid + 256 * t;
        int rr = idx >> 7, kk = idx & 127;
        As[rr][kk] = A[(r0 + rr) * 128 + kk];
        Bs[rr][kk] = B[(n0 + rr) * 128 + kk];
    }
    __syncthreads();
    const int n = tid & 31;
    const int rg = tid >> 5;
    const float bv = bias ? bias[n0 + n] : 0.0f;
    float acc0 = bv, acc1 = bv, acc2 = bv, acc3 = bv;
#pragma unroll 8
    for (int k = 0; k < 128; ++k) {
        float b_ = Bs[n][k];
        acc0 += As[rg][k] * b_;
        acc1 += As[rg + 8][k] * b_;
        acc2 += As[rg + 16][k] * b_;
        acc3 += As[rg + 24][k] * b_;
    }
    const int gn = n0 + n;
    float accs[4] = {acc0, acc1, acc2, acc3};
#pragma unroll
    for (int ri = 0; ri < 4; ++ri) {
        int r = r0 + rg + 8 * ri;
        float v = accs[ri];
        if (X) v += X[r * Nd + gn];
        C[r * Nd + gn] = v;
    }
}

// ---------------------------------------------------------------------------
// W2[c,o] = lo_w[o,c] * sum_j a[j,c] * tx[j,o]      (128x128 output)
// ---------------------------------------------------------------------------
__global__ __launch_bounds__(256) void atat_k(const float* __restrict__ a,
    const float* __restrict__ tx, const float* __restrict__ lo_w,
    float* __restrict__ W2)
{
    __shared__ float As[64][33];
    __shared__ float Ts[64][33];
    const int c0 = blockIdx.x * 32;
    const int o0 = blockIdx.y * 32;
    const int tid = threadIdx.x;
    const int o = tid & 31;
    const int cg = tid >> 5;
    float acc0 = 0, acc1 = 0, acc2 = 0, acc3 = 0;
    for (int j0 = 0; j0 < L_SEQ; j0 += 64) {
        __syncthreads();
#pragma unroll
        for (int t = 0; t < 8; ++t) {
            int idx = tid + 256 * t;
            int jj = idx >> 5, cc = idx & 31;
            As[jj][cc] = a[(j0 + jj) * 128 + c0 + cc];
            Ts[jj][cc] = tx[(j0 + jj) * 128 + o0 + cc];
        }
        __syncthreads();
#pragma unroll 4
        for (int jj = 0; jj < 64; ++jj) {
            float tv = Ts[jj][o];
            acc0 += As[jj][cg] * tv;
            acc1 += As[jj][cg + 8] * tv;
            acc2 += As[jj][cg + 16] * tv;
            acc3 += As[jj][cg + 24] * tv;
        }
    }
    float accs[4] = {acc0, acc1, acc2, acc3};
#pragma unroll
    for (int ci = 0; ci < 4; ++ci) {
        int c = c0 + cg + 8 * ci;
        int og = o0 + o;
        W2[c * 128 + og] = lo_w[og * 128 + c] * accs[ci];
    }
}

// ---------------------------------------------------------------------------
// tsum[o] = sum_j tx[j,o]
// ---------------------------------------------------------------------------
__global__ __launch_bounds__(256) void tsum_k(const float* __restrict__ tx,
                                              float* __restrict__ ts)
{
    __shared__ float part[256];
    const int tid = threadIdx.x;
    const int o = tid & 127, half = tid >> 7;
    float s = 0.0f;
    for (int j = half * 384; j < half * 384 + 384; ++j) s += tx[j * 128 + o];
    part[tid] = s;
    __syncthreads();
    if (tid < 128) ts[tid] = part[tid] + part[tid + 128];
}

// ---------------------------------------------------------------------------
// y1[768x128] = X + A @ W2 + lo_b ⊙ tsum   (W2 is [K=128][N=128] row-major)
// ---------------------------------------------------------------------------
__global__ __launch_bounds__(256) void gemm_nn_epi(const float* __restrict__ A,
    const float* __restrict__ Bw, const float* __restrict__ lo_b,
    const float* __restrict__ tsum, const float* __restrict__ X,
    float* __restrict__ C)
{
    __shared__ float As[32][129];
    __shared__ float Bs[128][33];
    const int r0 = blockIdx.x * 32;
    const int n0 = blockIdx.y * 32;
    const int tid = threadIdx.x;
#pragma unroll
    for (int t = 0; t < 16; ++t) {
        int idx = tid + 256 * t;
        int rr = idx >> 7, kk = idx & 127;
        As[rr][kk] = A[(r0 + rr) * 128 + kk];
        int k2 = idx >> 5, nn = idx & 31;
        Bs[k2][nn] = Bw[k2 * 128 + n0 + nn];
    }
    __syncthreads();
    const int n = tid & 31;
    const int rg = tid >> 5;
    const int gn = n0 + n;
    const float bv = lo_b[gn] * tsum[gn];
    float acc0 = bv, acc1 = bv, acc2 = bv, acc3 = bv;
#pragma unroll 8
    for (int k = 0; k < 128; ++k) {
        float b_ = Bs[k][n];
        acc0 += As[rg][k] * b_;
        acc1 += As[rg + 8][k] * b_;
        acc2 += As[rg + 16][k] * b_;
        acc3 += As[rg + 24][k] * b_;
    }
    float accs[4] = {acc0, acc1, acc2, acc3};
#pragma unroll
    for (int ri = 0; ri < 4; ++ri) {
        int r = r0 + rg + 8 * ri;
        C[r * 128 + gn] = X[r * 128 + gn] + accs[ri];
    }
}

// ---------------------------------------------------------------------------
// LayerNorm over last dim (128). One 64-thread block per row; 2 cols/thread.
// COMBINE: out = x + x1 + LN(y)   else   out = LN(y)
// ---------------------------------------------------------------------------
template <bool COMBINE>
__global__ __launch_bounds__(64) void ln_k(const float* __restrict__ y,
    const float* __restrict__ g, const float* __restrict__ b,
    const float* __restrict__ x, const float* __restrict__ x1,
    float* __restrict__ out)
{
    const int r = blockIdx.x;
    const int t = threadIdx.x;
    float v0 = y[r * 128 + t];
    float v1 = y[r * 128 + t + 64];
    float s = v0 + v1;
#pragma unroll
    for (int off = 32; off > 0; off >>= 1) s += __shfl_xor(s, off);
    float mean = s * (1.0f / 128.0f);
    float d0 = v0 - mean, d1 = v1 - mean;
    float q = d0 * d0 + d1 * d1;
#pragma unroll
    for (int off = 32; off > 0; off >>= 1) q += __shfl_xor(q, off);
    float rs = rsqrtf(q * (1.0f / 128.0f) + 1e-5f);
    float o0 = d0 * rs * g[t] + b[t];
    float o1 = d1 * rs * g[t + 64] + b[t + 64];
    if (COMBINE) {
        out[r * 128 + t] = x[r * 128 + t] + x1[r * 128 + t] + o0;
        out[r * 128 + t + 64] = x[r * 128 + t + 64] + x1[r * 128 + t + 64] + o1;
    } else {
        out[r * 128 + t] = o0;
        out[r * 128 + t + 64] = o1;
    }
}

// ---------------------------------------------------------------------------
// MHA core: qkv[768][384] (q|k|v), H=8 heads, DH=16, scale=0.25.
// Grid (8 heads, 12 chunks of 64 query rows). Block 256 = 64 rows x 4 key
// partitions. Online softmax per (row, partition); LDS merge of 4 partials.
// ---------------------------------------------------------------------------
__global__ __launch_bounds__(256) void attn_k(const float* __restrict__ qkv,
                                              float* __restrict__ out)
{
    const int h = blockIdx.x;
    const int chunk = blockIdx.y;
    const int tid = threadIdx.x;
    const int r = tid & 63;
    const int jp = tid >> 6;   // key partition 0..3 (192 keys each)
    const int qi = chunk * 64 + r;

    __shared__ float Ks[192][17];
    __shared__ float Vs[192][17];
    __shared__ float sm[4][64];
    __shared__ float sl[4][64];
    __shared__ float sacc[4][64][16];

    float q[16];
    {
        const float4* qrow = (const float4*)(qkv + qi * 384 + h * 16);
#pragma unroll
        for (int d4 = 0; d4 < 4; ++d4) {
            float4 tq = qrow[d4];
            q[d4 * 4 + 0] = tq.x; q[d4 * 4 + 1] = tq.y;
            q[d4 * 4 + 2] = tq.z; q[d4 * 4 + 3] = tq.w;
        }
    }
    float m = -1e30f, l = 0.0f;
    float acc[16];
#pragma unroll
    for (int d = 0; d < 16; ++d) acc[d] = 0.0f;

    for (int s = 0; s < 4; ++s) {   // 4 staging passes of 48 keys/partition
        __syncthreads();
        // stage rows: LDS row t covers key j = (t/48)*192 + s*48 + (t%48)
#pragma unroll
        for (int t = 0; t < 12; ++t) {
            int idx = tid + 256 * t;
            int row = idx >> 4, d = idx & 15;
            int j = (row / 48) * 192 + s * 48 + (row % 48);
            Ks[row][d] = qkv[j * 384 + 128 + h * 16 + d];
            Vs[row][d] = qkv[j * 384 + 256 + h * 16 + d];
        }
        __syncthreads();
        const int tbase = jp * 48;
        for (int jj = 0; jj < 48; ++jj) {
            int t = tbase + jj;
            float sc = 0.0f;
#pragma unroll
            for (int d = 0; d < 16; ++d) sc += q[d] * Ks[t][d];
            sc *= 0.25f;
            float p;
            if (sc > m) {
                float f = __expf(m - sc);   // 0 when m == -1e30
                l *= f;
#pragma unroll
                for (int d = 0; d < 16; ++d) acc[d] *= f;
                m = sc;
                p = 1.0f;
            } else {
                p = __expf(sc - m);
            }
            l += p;
#pragma unroll
            for (int d = 0; d < 16; ++d) acc[d] += p * Vs[t][d];
        }
    }
    sm[jp][r] = m;
    sl[jp][r] = l;
#pragma unroll
    for (int d = 0; d < 16; ++d) sacc[jp][r][d] = acc[d];
    __syncthreads();
    if (tid < 64) {
        float M_ = sm[0][tid];
#pragma unroll
        for (int p2 = 1; p2 < 4; ++p2) M_ = fmaxf(M_, sm[p2][tid]);
        float L_ = 0.0f;
        float o16[16];
#pragma unroll
        for (int d = 0; d < 16; ++d) o16[d] = 0.0f;
#pragma unroll
        for (int p2 = 0; p2 < 4; ++p2) {
            float f = __expf(sm[p2][tid] - M_);
            L_ += sl[p2][tid] * f;
#pragma unroll
            for (int d = 0; d < 16; ++d) o16[d] += sacc[p2][tid][d] * f;
        }
        float inv = 1.0f / L_;
        int qo = chunk * 64 + tid;
#pragma unroll
        for (int d = 0; d < 16; ++d) out[qo * 128 + h * 16 + d] = o16[d] * inv;
    }
}

// ---------------------------------------------------------------------------
extern "C" void kernel_launch(void* const* d_in, const int* in_sizes, int n_in,
                              void* d_out, int out_size, void* d_ws, size_t ws_size,
                              hipStream_t stream)
{
    const float* x_in      = (const float*)d_in[0];
    const float* cop_l_w   = (const float*)d_in[1];
    const float* cop_l_b   = (const float*)d_in[2];
    const float* cop_lo_w  = (const float*)d_in[3];
    const float* cop_lo_b  = (const float*)d_in[4];
    const float* cop_out_w = (const float*)d_in[5];
    const float* cop_out_b = (const float*)d_in[6];
    const float* cop_ln_g  = (const float*)d_in[7];
    const float* cop_ln_b  = (const float*)d_in[8];
    const float* qkv_w     = (const float*)d_in[9];
    const float* qkv_b     = (const float*)d_in[10];
    const float* mha_out_w = (const float*)d_in[11];
    const float* mha_out_b = (const float*)d_in[12];
    const float* mha_ln_g  = (const float*)d_in[13];
    const float* mha_ln_b  = (const float*)d_in[14];
    const float* l1_w      = (const float*)d_in[15];
    const float* l1_b      = (const float*)d_in[16];

    float* ws = (float*)d_ws;
    float* xA   = ws + 0 * P_SZ;
    float* xB   = ws + 1 * P_SZ;
    float* a_   = ws + 2 * P_SZ;
    float* tx_  = ws + 3 * P_SZ;
    float* x1_  = ws + 4 * P_SZ;
    float* y_   = ws + 5 * P_SZ;
    float* qkv_ = ws + 6 * P_SZ;          // 3*P_SZ floats
    float* o_   = ws + 9 * P_SZ;
    float* W2_  = ws + 10 * P_SZ;         // 16384
    float* ts_  = ws + 10 * P_SZ + 16384; // 128

    const float* xc = x_in;
    float* xn = xA;

    for (int i = 0; i < 6; ++i) {
        const float* lw  = cop_l_w   + i * 16384;
        const float* lb  = cop_l_b   + i * 128;
        const float* low = cop_lo_w  + i * 16384;
        const float* lob = cop_lo_b  + i * 128;
        const float* ow  = cop_out_w + i * 16384;
        const float* ob  = cop_out_b + i * 128;
        const float* lg1 = cop_ln_g  + i * 128;
        const float* lb1 = cop_ln_b  + i * 128;
        const float* qw  = qkv_w     + i * 49152;
        const float* qb  = qkv_b     + i * 384;
        const float* mw  = mha_out_w + i * 16384;
        const float* mb  = mha_out_b + i * 128;
        const float* lg2 = mha_ln_g  + i * 128;
        const float* lb2 = mha_ln_b  + i * 128;

        // ---- outer-product branch (algebraically reduced) ----
        gemm_bt<<<dim3(24, 4), 256, 0, stream>>>(xc, lw, lb, nullptr, a_, 128);
        gemm_bt<<<dim3(24, 4), 256, 0, stream>>>(xc, ow, ob, nullptr, tx_, 128);
        tsum_k<<<1, 256, 0, stream>>>(tx_, ts_);
        atat_k<<<dim3(4, 4), 256, 0, stream>>>(a_, tx_, low, W2_);
        gemm_nn_epi<<<dim3(24, 4), 256, 0, stream>>>(a_, W2_, lob, ts_, xc, y_);
        ln_k<false><<<768, 64, 0, stream>>>(y_, lg1, lb1, nullptr, nullptr, x1_);

        // ---- MHA branch ----
        gemm_bt<<<dim3(24, 12), 256, 0, stream>>>(xc, qw, qb, nullptr, qkv_, 384);
        attn_k<<<dim3(8, 12), 256, 0, stream>>>(qkv_, o_);
        gemm_bt<<<dim3(24, 4), 256, 0, stream>>>(o_, mw, mb, xc, y_, 128);

        // ---- LN2 + combine: xn = x + x1 + LN(y2) ----
        ln_k<true><<<768, 64, 0, stream>>>(y_, lg2, lb2, xc, x1_, xn);

        xc = xn;
        xn = (xc == xA) ? xB : xA;
    }

    // final projection
    gemm_bt<<<dim3(24, 4), 256, 0, stream>>>(xc, l1_w, l1_b, nullptr,
                                             (float*)d_out, 128);
}

// Round 2
// 378.777 us; speedup vs baseline: 2.0790x; 2.0790x over previous
//
#include <hip/hip_runtime.h>

// Sizes fixed by the problem: B=1, L=768, D=128, H=8, DH=16, N=6 layers.
#define L_SEQ 768
#define D_MOD 128
#define P_SZ  (L_SEQ * D_MOD)   // 98304

// ---------------------------------------------------------------------------
// Generic BT GEMM body used by several kernels:
// C[768 x 128] = A[768 x 128] @ B[128 x 128]^T + bias (+X). Tile 32x32.
// ---------------------------------------------------------------------------
__global__ __launch_bounds__(256) void gemm_bt(const float* __restrict__ A,
    const float* __restrict__ B, const float* __restrict__ bias,
    const float* __restrict__ X, float* __restrict__ C, int Nd)
{
    __shared__ float As[32][129];
    __shared__ float Bs[32][129];
    const int r0 = blockIdx.x * 32;
    const int n0 = blockIdx.y * 32;
    const int tid = threadIdx.x;
#pragma unroll
    for (int t = 0; t < 16; ++t) {
        int idx = tid + 256 * t;
        int rr = idx >> 7, kk = idx & 127;
        As[rr][kk] = A[(r0 + rr) * 128 + kk];
        Bs[rr][kk] = B[(n0 + rr) * 128 + kk];
    }
    __syncthreads();
    const int n = tid & 31;
    const int rg = tid >> 5;
    const float bv = bias ? bias[n0 + n] : 0.0f;
    float acc0 = bv, acc1 = bv, acc2 = bv, acc3 = bv;
#pragma unroll 8
    for (int k = 0; k < 128; ++k) {
        float b_ = Bs[n][k];
        acc0 += As[rg][k] * b_;
        acc1 += As[rg + 8][k] * b_;
        acc2 += As[rg + 16][k] * b_;
        acc3 += As[rg + 24][k] * b_;
    }
    const int gn = n0 + n;
    float accs[4] = {acc0, acc1, acc2, acc3};
#pragma unroll
    for (int ri = 0; ri < 4; ++ri) {
        int r = r0 + rg + 8 * ri;
        float v = accs[ri];
        if (X) v += X[r * Nd + gn];
        C[r * Nd + gn] = v;
    }
}

// ---------------------------------------------------------------------------
// Mega-GEMM: from xc compute  a = x@lw^T+lb   (blockIdx.y 0..3)
//                             tx = x@ow^T+ob  (blockIdx.y 4..7)
//                             qkv = x@qw^T+qb (blockIdx.y 8..19)
// Grid (24, 20) = 480 blocks.
// ---------------------------------------------------------------------------
__global__ __launch_bounds__(256) void mega1(const float* __restrict__ x,
    const float* __restrict__ lw, const float* __restrict__ lb,
    const float* __restrict__ ow, const float* __restrict__ ob,
    const float* __restrict__ qw, const float* __restrict__ qb,
    float* __restrict__ a, float* __restrict__ tx, float* __restrict__ qkv)
{
    __shared__ float As[32][129];
    __shared__ float Bs[32][129];
    const int y = blockIdx.y;
    const float* W; const float* bias; float* out; int n0, ldC;
    if (y < 4)      { W = lw; bias = lb; out = a;   n0 = y * 32;       ldC = 128; }
    else if (y < 8) { W = ow; bias = ob; out = tx;  n0 = (y - 4) * 32; ldC = 128; }
    else            { W = qw; bias = qb; out = qkv; n0 = (y - 8) * 32; ldC = 384; }

    const int r0 = blockIdx.x * 32;
    const int tid = threadIdx.x;
#pragma unroll
    for (int t = 0; t < 16; ++t) {
        int idx = tid + 256 * t;
        int rr = idx >> 7, kk = idx & 127;
        As[rr][kk] = x[(r0 + rr) * 128 + kk];
        Bs[rr][kk] = W[(n0 + rr) * 128 + kk];
    }
    __syncthreads();
    const int n = tid & 31;
    const int rg = tid >> 5;
    const float bv = bias[n0 + n];
    float acc0 = bv, acc1 = bv, acc2 = bv, acc3 = bv;
#pragma unroll 8
    for (int k = 0; k < 128; ++k) {
        float b_ = Bs[n][k];
        acc0 += As[rg][k] * b_;
        acc1 += As[rg + 8][k] * b_;
        acc2 += As[rg + 16][k] * b_;
        acc3 += As[rg + 24][k] * b_;
    }
    const int gn = n0 + n;
    float accs[4] = {acc0, acc1, acc2, acc3};
#pragma unroll
    for (int ri = 0; ri < 4; ++ri) {
        int r = r0 + rg + 8 * ri;
        out[r * ldC + gn] = accs[ri];
    }
}

// ---------------------------------------------------------------------------
// Blocks 0..15: W2T[o][c] = lo_w[o,c] * sum_j a[j,c]*tx[j,o]   (coalesced out)
// Block  16  : ts[o] = sum_j tx[j,o]
// ---------------------------------------------------------------------------
__global__ __launch_bounds__(256) void atat_tsum(const float* __restrict__ a,
    const float* __restrict__ tx, const float* __restrict__ lo_w,
    float* __restrict__ W2T, float* __restrict__ ts)
{
    __shared__ float As[64][33];
    __shared__ float Ts[64][33];
    const int tid = threadIdx.x;
    if (blockIdx.x == 16) {   // tsum
        float* part = &As[0][0];
        const int o = tid & 127, half = tid >> 7;
        float s = 0.0f;
        for (int j = half * 384; j < half * 384 + 384; ++j) s += tx[j * 128 + o];
        part[tid] = s;
        __syncthreads();
        if (tid < 128) ts[tid] = part[tid] + part[tid + 128];
        return;
    }
    const int c0 = (blockIdx.x & 3) * 32;
    const int o0 = (blockIdx.x >> 2) * 32;
    const int cl = tid & 31;    // c lane  -> coalesced output
    const int og = tid >> 5;    // o group 0..7
    float acc0 = 0, acc1 = 0, acc2 = 0, acc3 = 0;
    for (int j0 = 0; j0 < L_SEQ; j0 += 64) {
        __syncthreads();
#pragma unroll
        for (int t = 0; t < 8; ++t) {
            int idx = tid + 256 * t;
            int jj = idx >> 5, cc = idx & 31;
            As[jj][cc] = a[(j0 + jj) * 128 + c0 + cc];
            Ts[jj][cc] = tx[(j0 + jj) * 128 + o0 + cc];
        }
        __syncthreads();
#pragma unroll 4
        for (int jj = 0; jj < 64; ++jj) {
            float av = As[jj][cl];
            acc0 += av * Ts[jj][og];
            acc1 += av * Ts[jj][og + 8];
            acc2 += av * Ts[jj][og + 16];
            acc3 += av * Ts[jj][og + 24];
        }
    }
    float accs[4] = {acc0, acc1, acc2, acc3};
#pragma unroll
    for (int oi = 0; oi < 4; ++oi) {
        int o = o0 + og + 8 * oi;
        W2T[o * 128 + c0 + cl] = lo_w[o * 128 + c0 + cl] * accs[oi];
    }
}

// ---------------------------------------------------------------------------
// Fused y1/y2 GEMM (both BT form, both add xc):
//   blockIdx.y 0..3: y1 = xc + a @ W2T^T + (lob*ts)      per-col bias
//   blockIdx.y 4..7: y2 = xc + o @ mw^T + mb
// Grid (24, 8).
// ---------------------------------------------------------------------------
__global__ __launch_bounds__(256) void ygemm(const float* __restrict__ a_,
    const float* __restrict__ W2T, const float* __restrict__ lob,
    const float* __restrict__ ts, const float* __restrict__ o_,
    const float* __restrict__ mw, const float* __restrict__ mb,
    const float* __restrict__ xc, float* __restrict__ y1, float* __restrict__ y2)
{
    __shared__ float As[32][129];
    __shared__ float Bs[32][129];
    const int y = blockIdx.y;
    const float *A, *B, *b1, *b2; float* C; int n0;
    if (y < 4) { A = a_; B = W2T; b1 = lob; b2 = ts;      C = y1; n0 = y * 32; }
    else       { A = o_; B = mw;  b1 = mb;  b2 = nullptr; C = y2; n0 = (y - 4) * 32; }

    const int r0 = blockIdx.x * 32;
    const int tid = threadIdx.x;
#pragma unroll
    for (int t = 0; t < 16; ++t) {
        int idx = tid + 256 * t;
        int rr = idx >> 7, kk = idx & 127;
        As[rr][kk] = A[(r0 + rr) * 128 + kk];
        Bs[rr][kk] = B[(n0 + rr) * 128 + kk];
    }
    __syncthreads();
    const int n = tid & 31;
    const int rg = tid >> 5;
    const int gn = n0 + n;
    const float bv = b2 ? b1[gn] * b2[gn] : b1[gn];
    float acc0 = bv, acc1 = bv, acc2 = bv, acc3 = bv;
#pragma unroll 8
    for (int k = 0; k < 128; ++k) {
        float b_ = Bs[n][k];
        acc0 += As[rg][k] * b_;
        acc1 += As[rg + 8][k] * b_;
        acc2 += As[rg + 16][k] * b_;
        acc3 += As[rg + 24][k] * b_;
    }
    float accs[4] = {acc0, acc1, acc2, acc3};
#pragma unroll
    for (int ri = 0; ri < 4; ++ri) {
        int r = r0 + rg + 8 * ri;
        C[r * 128 + gn] = xc[r * 128 + gn] + accs[ri];
    }
}

// ---------------------------------------------------------------------------
// Attention: grid (8 heads, 48 chunks of 16 query rows); block 256 =
// 16 rows x 16 key-partitions (48 keys each). Online softmax per partition,
// 16-way LDS merge. qkv row layout: [q(128) | k(128) | v(128)] x 3 -> 384.
// ---------------------------------------------------------------------------
__global__ __launch_bounds__(256) void attn2(const float* __restrict__ qkv,
                                             float* __restrict__ out)
{
    const int h = blockIdx.x;
    const int chunk = blockIdx.y;
    const int tid = threadIdx.x;
    const int r = tid & 15;      // row within chunk
    const int part = tid >> 4;   // key partition 0..15
    const int qi = chunk * 16 + r;

    __shared__ float Ks[192][20];
    __shared__ float Vs[192][20];
    __shared__ float sm[16][16];        // [part][row]
    __shared__ float sl[16][16];
    __shared__ float sacc[16][16][16];  // [part][row][d]

    float q[16];
    {
        const float4* qrow = (const float4*)(qkv + qi * 384 + h * 16);
#pragma unroll
        for (int d4 = 0; d4 < 4; ++d4) {
            float4 tq = qrow[d4];
            q[d4 * 4 + 0] = tq.x; q[d4 * 4 + 1] = tq.y;
            q[d4 * 4 + 2] = tq.z; q[d4 * 4 + 3] = tq.w;
        }
    }
    float m = -1e30f, l = 0.0f;
    float acc[16];
#pragma unroll
    for (int d = 0; d < 16; ++d) acc[d] = 0.0f;

    for (int s = 0; s < 4; ++s) {   // stage 192 keys per pass
        __syncthreads();
#pragma unroll
        for (int t = 0; t < 3; ++t) {
            int idx = tid + 256 * t;       // 0..767
            int row = idx >> 2, d4 = idx & 3;
            int j = s * 192 + row;
            float4 kv = *(const float4*)(qkv + j * 384 + 128 + h * 16 + d4 * 4);
            float4 vv = *(const float4*)(qkv + j * 384 + 256 + h * 16 + d4 * 4);
            *(float4*)(&Ks[row][d4 * 4]) = kv;
            *(float4*)(&Vs[row][d4 * 4]) = vv;
        }
        __syncthreads();
        const int tb = part * 12;
#pragma unroll 2
        for (int jj = 0; jj < 12; ++jj) {
            int t = tb + jj;
            float sc = 0.0f;
#pragma unroll
            for (int d = 0; d < 16; ++d) sc += q[d] * Ks[t][d];
            sc *= 0.25f;
            float p;
            if (sc > m) {
                float f = __expf(m - sc);   // 0 when m == -1e30
                l *= f;
#pragma unroll
                for (int d = 0; d < 16; ++d) acc[d] *= f;
                m = sc;
                p = 1.0f;
            } else {
                p = __expf(sc - m);
            }
            l += p;
#pragma unroll
            for (int d = 0; d < 16; ++d) acc[d] += p * Vs[t][d];
        }
    }
    sm[part][r] = m;
    sl[part][r] = l;
#pragma unroll
    for (int d = 0; d < 16; ++d) sacc[part][r][d] = acc[d];
    __syncthreads();

    // merge: each thread owns (row, d)
    const int row = tid >> 4, d = tid & 15;
    float M_ = sm[0][row];
#pragma unroll
    for (int p = 1; p < 16; ++p) M_ = fmaxf(M_, sm[p][row]);
    float L_ = 0.0f, o = 0.0f;
#pragma unroll
    for (int p = 0; p < 16; ++p) {
        float f = __expf(sm[p][row] - M_);
        L_ += sl[p][row] * f;
        o += sacc[p][row][d] * f;
    }
    out[(chunk * 16 + row) * 128 + h * 16 + d] = o / L_;
}

// ---------------------------------------------------------------------------
// Fused epilogue: xn = x + LN1(y1) + LN2(y2). One 64-thread block per row.
// ---------------------------------------------------------------------------
__global__ __launch_bounds__(64) void lncomb(const float* __restrict__ y1,
    const float* __restrict__ y2, const float* __restrict__ g1,
    const float* __restrict__ b1, const float* __restrict__ g2,
    const float* __restrict__ b2, const float* __restrict__ x,
    float* __restrict__ out)
{
    const int r = blockIdx.x;
    const int t = threadIdx.x;

    float o0a, o1a, o0b, o1b;
    {
        float v0 = y1[r * 128 + t], v1 = y1[r * 128 + t + 64];
        float s = v0 + v1;
#pragma unroll
        for (int off = 32; off > 0; off >>= 1) s += __shfl_xor(s, off);
        float mean = s * (1.0f / 128.0f);
        float d0 = v0 - mean, d1 = v1 - mean;
        float qv = d0 * d0 + d1 * d1;
#pragma unroll
        for (int off = 32; off > 0; off >>= 1) qv += __shfl_xor(qv, off);
        float rs = rsqrtf(qv * (1.0f / 128.0f) + 1e-5f);
        o0a = d0 * rs * g1[t] + b1[t];
        o1a = d1 * rs * g1[t + 64] + b1[t + 64];
    }
    {
        float v0 = y2[r * 128 + t], v1 = y2[r * 128 + t + 64];
        float s = v0 + v1;
#pragma unroll
        for (int off = 32; off > 0; off >>= 1) s += __shfl_xor(s, off);
        float mean = s * (1.0f / 128.0f);
        float d0 = v0 - mean, d1 = v1 - mean;
        float qv = d0 * d0 + d1 * d1;
#pragma unroll
        for (int off = 32; off > 0; off >>= 1) qv += __shfl_xor(qv, off);
        float rs = rsqrtf(qv * (1.0f / 128.0f) + 1e-5f);
        o0b = d0 * rs * g2[t] + b2[t];
        o1b = d1 * rs * g2[t + 64] + b2[t + 64];
    }
    out[r * 128 + t]      = x[r * 128 + t]      + o0a + o0b;
    out[r * 128 + t + 64] = x[r * 128 + t + 64] + o1a + o1b;
}

// ---------------------------------------------------------------------------
extern "C" void kernel_launch(void* const* d_in, const int* in_sizes, int n_in,
                              void* d_out, int out_size, void* d_ws, size_t ws_size,
                              hipStream_t stream)
{
    const float* x_in      = (const float*)d_in[0];
    const float* cop_l_w   = (const float*)d_in[1];
    const float* cop_l_b   = (const float*)d_in[2];
    const float* cop_lo_w  = (const float*)d_in[3];
    const float* cop_lo_b  = (const float*)d_in[4];
    const float* cop_out_w = (const float*)d_in[5];
    const float* cop_out_b = (const float*)d_in[6];
    const float* cop_ln_g  = (const float*)d_in[7];
    const float* cop_ln_b  = (const float*)d_in[8];
    const float* qkv_w     = (const float*)d_in[9];
    const float* qkv_b     = (const float*)d_in[10];
    const float* mha_out_w = (const float*)d_in[11];
    const float* mha_out_b = (const float*)d_in[12];
    const float* mha_ln_g  = (const float*)d_in[13];
    const float* mha_ln_b  = (const float*)d_in[14];
    const float* l1_w      = (const float*)d_in[15];
    const float* l1_b      = (const float*)d_in[16];

    float* ws = (float*)d_ws;
    float* xA   = ws + 0 * P_SZ;
    float* xB   = ws + 1 * P_SZ;
    float* a_   = ws + 2 * P_SZ;
    float* tx_  = ws + 3 * P_SZ;
    float* y1_  = ws + 4 * P_SZ;
    float* y2_  = ws + 5 * P_SZ;
    float* qkv_ = ws + 6 * P_SZ;          // 3*P_SZ floats
    float* o_   = ws + 9 * P_SZ;
    float* W2T_ = ws + 10 * P_SZ;         // 16384
    float* ts_  = ws + 10 * P_SZ + 16384; // 128

    const float* xc = x_in;
    float* xn = xA;

    for (int i = 0; i < 6; ++i) {
        const float* lw  = cop_l_w   + i * 16384;
        const float* lb  = cop_l_b   + i * 128;
        const float* low = cop_lo_w  + i * 16384;
        const float* lob = cop_lo_b  + i * 128;
        const float* ow  = cop_out_w + i * 16384;
        const float* ob  = cop_out_b + i * 128;
        const float* lg1 = cop_ln_g  + i * 128;
        const float* lb1 = cop_ln_b  + i * 128;
        const float* qw  = qkv_w     + i * 49152;
        const float* qb  = qkv_b     + i * 384;
        const float* mw  = mha_out_w + i * 16384;
        const float* mb  = mha_out_b + i * 128;
        const float* lg2 = mha_ln_g  + i * 128;
        const float* lb2 = mha_ln_b  + i * 128;

        // 1. a, tx, qkv from xc (480 blocks)
        mega1<<<dim3(24, 20), 256, 0, stream>>>(xc, lw, lb, ow, ob, qw, qb,
                                                a_, tx_, qkv_);
        // 2. attention (384 blocks)
        attn2<<<dim3(8, 48), 256, 0, stream>>>(qkv_, o_);
        // 3. W2T + tsum (17 blocks)
        atat_tsum<<<17, 256, 0, stream>>>(a_, tx_, low, W2T_, ts_);
        // 4. y1 and y2 (192 blocks)
        ygemm<<<dim3(24, 8), 256, 0, stream>>>(a_, W2T_, lob, ts_, o_, mw, mb,
                                               xc, y1_, y2_);
        // 5. xn = x + LN(y1) + LN(y2) (768 blocks)
        lncomb<<<768, 64, 0, stream>>>(y1_, y2_, lg1, lb1, lg2, lb2, xc, xn);

        xc = xn;
        xn = (xc == xA) ? xB : xA;
    }

    // final projection
    gemm_bt<<<dim3(24, 4), 256, 0, stream>>>(xc, l1_w, l1_b, nullptr,
                                             (float*)d_out, 128);
}

// Round 4
// 299.893 us; speedup vs baseline: 2.6258x; 1.2630x over previous
//
#include <hip/hip_runtime.h>

// Sizes fixed by the problem: B=1, L=768, D=128, H=8, DH=16, N=6 layers.
#define L_SEQ 768
#define P_SZ  (L_SEQ * 128)   // 98304

__device__ __forceinline__ unsigned short f2bf(float x) {
    unsigned int u = __float_as_uint(x);
    unsigned int r = (u + 0x7fffu + ((u >> 16) & 1u)) >> 16;
    return (unsigned short)r;
}

// ---------------------------------------------------------------------------
// mega1: from x compute a = x@lw^T+lb, tx = x@ow^T+ob, qkv = x@qw^T+qb.
// Grid (24 row-tiles of 32, 10 col-tiles of 64). B staged in LDS (b128 reads),
// A read directly from global (L2-resident, broadcast-dedup), 2x4 reg tile.
// ---------------------------------------------------------------------------
__global__ __launch_bounds__(256) void mega1(const float* __restrict__ x,
    const float* __restrict__ lw, const float* __restrict__ lb,
    const float* __restrict__ ow, const float* __restrict__ ob,
    const float* __restrict__ qw, const float* __restrict__ qb,
    float* __restrict__ a, float* __restrict__ tx, float* __restrict__ qkv)
{
    __shared__ float Bs[64][132];
    const int ct = blockIdx.y;
    const float* W; const float* bias; float* out; int ldC, colbase;
    if (ct < 2)      { W = lw; bias = lb; out = a;   ldC = 128; colbase = ct * 64; }
    else if (ct < 4) { W = ow; bias = ob; out = tx;  ldC = 128; colbase = (ct - 2) * 64; }
    else             { W = qw; bias = qb; out = qkv; ldC = 384; colbase = (ct - 4) * 64; }
    const int tid = threadIdx.x;
#pragma unroll
    for (int t = 0; t < 8; ++t) {
        int idx = tid + 256 * t;
        int row = idx >> 5, f4 = idx & 31;
        *(float4*)&Bs[row][f4 * 4] = *(const float4*)&W[(colbase + row) * 128 + f4 * 4];
    }
    __syncthreads();
    const int rg = tid >> 4, ng = tid & 15;
    const int r0 = blockIdx.x * 32;
    const int r1 = r0 + rg, r2 = r0 + rg + 16;
    float accs[2][4];
#pragma unroll
    for (int c = 0; c < 4; ++c) {
        float bv = bias[colbase + ng + 16 * c];
        accs[0][c] = bv; accs[1][c] = bv;
    }
    const float* A1 = x + r1 * 128;
    const float* A2 = x + r2 * 128;
#pragma unroll 8
    for (int kk = 0; kk < 32; ++kk) {
        float4 a1 = *(const float4*)&A1[kk * 4];
        float4 a2 = *(const float4*)&A2[kk * 4];
#pragma unroll
        for (int c = 0; c < 4; ++c) {
            float4 b = *(const float4*)&Bs[ng + 16 * c][kk * 4];
            accs[0][c] += a1.x * b.x + a1.y * b.y + a1.z * b.z + a1.w * b.w;
            accs[1][c] += a2.x * b.x + a2.y * b.y + a2.z * b.z + a2.w * b.w;
        }
    }
#pragma unroll
    for (int c = 0; c < 4; ++c) {
        int gc = colbase + ng + 16 * c;
        out[r1 * ldC + gc] = accs[0][c];
        out[r2 * ldC + gc] = accs[1][c];
    }
}

// ---------------------------------------------------------------------------
// K2: fused attention (blocks 0..191) + atat partials/tsum (blocks 192..255).
//
// attention: (h, chunk of 32 q-rows); 256 thr = 8 row-groups(4 rows) x 32
// key-partitions. Keys lane-interleaved (j = jj*32+p). 2 staging passes of
// 384 keys f32 in LDS. Defer-max online softmax (thr=8). Merge via LDS with
// bf16-packed partial accumulators reusing the K/V buffer.
//
// atat: (jc 0..15, ot 0..3): Mpart[jc][o][c] = sum_{j in jc} a[j,c]*tx[j,o]
// (48 j's), float4 outer-product; plus tsum partials.
// ---------------------------------------------------------------------------
__global__ __launch_bounds__(256) void k2(const float* __restrict__ qkv,
    const float* __restrict__ a_, const float* __restrict__ tx_,
    float* __restrict__ o_, float* __restrict__ Mpart, float* __restrict__ tspart)
{
    __shared__ __align__(16) char smem[61440];
    const int bid = blockIdx.x;
    const int tid = threadIdx.x;
    if (bid < 192) {
        float* Ks = (float*)smem;        // [384][20]
        float* Vs = Ks + 384 * 20;       // [384][20]
        const int h = bid / 24;
        const int ch = bid % 24;
        const int base = ch * 32;
        const int lane = tid & 63;
        const int w = tid >> 6;
        const int p = lane & 31;
        const int rgidx = w * 2 + (lane >> 5);

        float q[4][16];
#pragma unroll
        for (int rr = 0; rr < 4; ++rr) {
            int r = base + rgidx * 4 + rr;
            const float4* qr = (const float4*)(qkv + r * 384 + h * 16);
#pragma unroll
            for (int s = 0; s < 4; ++s) {
                float4 v = qr[s];
                q[rr][s * 4 + 0] = v.x; q[rr][s * 4 + 1] = v.y;
                q[rr][s * 4 + 2] = v.z; q[rr][s * 4 + 3] = v.w;
            }
        }
        float m[4], l[4], acc[4][16];
#pragma unroll
        for (int rr = 0; rr < 4; ++rr) {
            m[rr] = -1e30f; l[rr] = 0.0f;
#pragma unroll
            for (int d = 0; d < 16; ++d) acc[rr][d] = 0.0f;
        }
        for (int ps = 0; ps < 2; ++ps) {
            __syncthreads();
#pragma unroll
            for (int t = 0; t < 6; ++t) {
                int idx = tid + 256 * t;     // 0..1535
                int jj = idx >> 2, seg = idx & 3;
                int j = ps * 384 + jj;
                *(float4*)&Ks[jj * 20 + seg * 4] =
                    *(const float4*)&qkv[j * 384 + 128 + h * 16 + seg * 4];
                *(float4*)&Vs[jj * 20 + seg * 4] =
                    *(const float4*)&qkv[j * 384 + 256 + h * 16 + seg * 4];
            }
            __syncthreads();
            for (int jj2 = 0; jj2 < 12; ++jj2) {
                int jl = jj2 * 32 + p;
                float k16[16], v16[16];
#pragma unroll
                for (int s = 0; s < 4; ++s) {
                    float4 kv = *(const float4*)&Ks[jl * 20 + s * 4];
                    k16[s * 4 + 0] = kv.x; k16[s * 4 + 1] = kv.y;
                    k16[s * 4 + 2] = kv.z; k16[s * 4 + 3] = kv.w;
                    float4 vv = *(const float4*)&Vs[jl * 20 + s * 4];
                    v16[s * 4 + 0] = vv.x; v16[s * 4 + 1] = vv.y;
                    v16[s * 4 + 2] = vv.z; v16[s * 4 + 3] = vv.w;
                }
#pragma unroll
                for (int rr = 0; rr < 4; ++rr) {
                    float sc = 0.0f;
#pragma unroll
                    for (int d = 0; d < 16; ++d) sc += q[rr][d] * k16[d];
                    sc *= 0.25f;
                    if (sc > m[rr] + 8.0f) {       // defer-max rescale (rare)
                        float f = __expf(m[rr] - sc);
                        l[rr] *= f;
#pragma unroll
                        for (int d = 0; d < 16; ++d) acc[rr][d] *= f;
                        m[rr] = sc;
                    }
                    float pe = __expf(sc - m[rr]);
                    l[rr] += pe;
#pragma unroll
                    for (int d = 0; d < 16; ++d) acc[rr][d] += pe * v16[d];
                }
            }
        }
        // ---- merge 32 partitions (reuse K/V LDS) ----
        __syncthreads();
        float* sm = (float*)smem;                               // [32][32]
        float* sl = sm + 1024;                                  // [32][32]
        unsigned short* sacc = (unsigned short*)(sl + 1024);    // [32][32][24]
#pragma unroll
        for (int rr = 0; rr < 4; ++rr) {
            int row = rgidx * 4 + rr;
            sm[p * 32 + row] = m[rr];
            sl[p * 32 + row] = l[rr];
            unsigned int wbuf[8];
#pragma unroll
            for (int d2 = 0; d2 < 8; ++d2) {
                unsigned int lo = f2bf(acc[rr][2 * d2]);
                unsigned int hi = f2bf(acc[rr][2 * d2 + 1]);
                wbuf[d2] = lo | (hi << 16);
            }
            uint4* dst = (uint4*)&sacc[(p * 32 + row) * 24];
            dst[0] = make_uint4(wbuf[0], wbuf[1], wbuf[2], wbuf[3]);
            dst[1] = make_uint4(wbuf[4], wbuf[5], wbuf[6], wbuf[7]);
        }
        __syncthreads();
        {
            const int row = tid >> 3, dp = tid & 7;
            float M = -1e30f;
#pragma unroll
            for (int pp = 0; pp < 32; ++pp) M = fmaxf(M, sm[pp * 32 + row]);
            float L = 0.0f, o0 = 0.0f, o1 = 0.0f;
#pragma unroll
            for (int pp = 0; pp < 32; ++pp) {
                float f = __expf(sm[pp * 32 + row] - M);
                L += sl[pp * 32 + row] * f;
                unsigned int wv = *(const unsigned int*)&sacc[(pp * 32 + row) * 24 + 2 * dp];
                o0 += f * __uint_as_float(wv << 16);
                o1 += f * __uint_as_float(wv & 0xffff0000u);
            }
            float inv = 1.0f / L;
            *(float2*)&o_[(base + row) * 128 + h * 16 + 2 * dp] =
                make_float2(o0 * inv, o1 * inv);
        }
    } else {
        // ---- atat partial + tsum partial ----
        const int idx = bid - 192;
        const int jc = idx >> 2, ot = idx & 3;
        const int j0 = jc * 48;
        float* As  = (float*)smem;      // [48][128]
        float* Ts  = As + 48 * 128;     // [48][32]
        float* red = Ts + 48 * 32;      // [256]
#pragma unroll
        for (int t = 0; t < 6; ++t) {
            int ix = tid + 256 * t;     // 0..1535
            int jj = ix >> 5, f4 = ix & 31;
            *(float4*)&As[jj * 128 + f4 * 4] =
                *(const float4*)&a_[(j0 + jj) * 128 + f4 * 4];
        }
        // Ts needs 48 rows x 8 float4 = 384 items; 256 threads -> 2 passes.
#pragma unroll
        for (int t = 0; t < 2; ++t) {
            int ix = tid + 256 * t;
            if (ix < 384) {
                int jj = ix >> 3, f4 = ix & 7;
                *(float4*)&Ts[jj * 32 + f4 * 4] =
                    *(const float4*)&tx_[(j0 + jj) * 128 + ot * 32 + f4 * 4];
            }
        }
        __syncthreads();
        const int c4 = tid & 31, owt = tid >> 5;
        float accm[4][4] = {};
#pragma unroll 4
        for (int jj = 0; jj < 48; ++jj) {
            float4 av = *(const float4*)&As[jj * 128 + c4 * 4];
            float4 tv = *(const float4*)&Ts[jj * 32 + owt * 4];
            float avv[4] = {av.x, av.y, av.z, av.w};
            float tvv[4] = {tv.x, tv.y, tv.z, tv.w};
#pragma unroll
            for (int oi = 0; oi < 4; ++oi)
#pragma unroll
                for (int ci = 0; ci < 4; ++ci)
                    accm[oi][ci] += avv[ci] * tvv[oi];
        }
#pragma unroll
        for (int oi = 0; oi < 4; ++oi) {
            *(float4*)&Mpart[jc * 16384 + (ot * 32 + owt * 4 + oi) * 128 + c4 * 4] =
                make_float4(accm[oi][0], accm[oi][1], accm[oi][2], accm[oi][3]);
        }
        {
            const int o = tid & 31, g = tid >> 5;
            float s = 0.0f;
#pragma unroll
            for (int jj = 0; jj < 6; ++jj) s += Ts[(g * 6 + jj) * 32 + o];
            red[g * 32 + o] = s;
        }
        __syncthreads();
        if (tid < 32) {
            float s = 0.0f;
#pragma unroll
            for (int g = 0; g < 8; ++g) s += red[g * 32 + tid];
            tspart[jc * 128 + ot * 32 + tid] = s;
        }
    }
}

// ---------------------------------------------------------------------------
// ygemm: grid (24, 4). yb 0,1: y1 = xc + a@W2T^T + lob*ts with
// W2T[o][c] = lo_w[o][c] * sum_jc Mpart[jc][o][c] built during staging.
// yb 2,3: y2 = xc + o@mw^T + mb.
// ---------------------------------------------------------------------------
__global__ __launch_bounds__(256) void ygemm(const float* __restrict__ a_,
    const float* __restrict__ o_, const float* __restrict__ Mpart,
    const float* __restrict__ lo_w, const float* __restrict__ lob,
    const float* __restrict__ tspart, const float* __restrict__ mw,
    const float* __restrict__ mb, const float* __restrict__ xc,
    float* __restrict__ y1, float* __restrict__ y2)
{
    __shared__ float Bs[64][132];
    const int yb = blockIdx.y;
    const int tid = threadIdx.x;
    const float* A; float* C; int colbase;
    if (yb < 2) {
        colbase = yb * 64; A = a_; C = y1;
#pragma unroll
        for (int t = 0; t < 8; ++t) {
            int idx = tid + 256 * t;
            int row = idx >> 5, f4 = idx & 31;
            int o = colbase + row;
            float4 s = make_float4(0.f, 0.f, 0.f, 0.f);
#pragma unroll
            for (int jc = 0; jc < 16; ++jc) {
                float4 mv = *(const float4*)&Mpart[jc * 16384 + o * 128 + f4 * 4];
                s.x += mv.x; s.y += mv.y; s.z += mv.z; s.w += mv.w;
            }
            float4 lw4 = *(const float4*)&lo_w[o * 128 + f4 * 4];
            s.x *= lw4.x; s.y *= lw4.y; s.z *= lw4.z; s.w *= lw4.w;
            *(float4*)&Bs[row][f4 * 4] = s;
        }
    } else {
        colbase = (yb - 2) * 64; A = o_; C = y2;
#pragma unroll
        for (int t = 0; t < 8; ++t) {
            int idx = tid + 256 * t;
            int row = idx >> 5, f4 = idx & 31;
            *(float4*)&Bs[row][f4 * 4] =
                *(const float4*)&mw[(colbase + row) * 128 + f4 * 4];
        }
    }
    __syncthreads();
    const int rg = tid >> 4, ng = tid & 15;
    const int r0 = blockIdx.x * 32;
    const int r1 = r0 + rg, r2 = r0 + rg + 16;
    float accs[2][4];
#pragma unroll
    for (int c = 0; c < 4; ++c) {
        int gc = colbase + ng + 16 * c;
        float bv;
        if (yb < 2) {
            float s = 0.0f;
#pragma unroll
            for (int jc = 0; jc < 16; ++jc) s += tspart[jc * 128 + gc];
            bv = lob[gc] * s;
        } else {
            bv = mb[gc];
        }
        accs[0][c] = bv; accs[1][c] = bv;
    }
    const float* A1 = A + r1 * 128;
    const float* A2 = A + r2 * 128;
#pragma unroll 8
    for (int kk = 0; kk < 32; ++kk) {
        float4 a1 = *(const float4*)&A1[kk * 4];
        float4 a2 = *(const float4*)&A2[kk * 4];
#pragma unroll
        for (int c = 0; c < 4; ++c) {
            float4 b = *(const float4*)&Bs[ng + 16 * c][kk * 4];
            accs[0][c] += a1.x * b.x + a1.y * b.y + a1.z * b.z + a1.w * b.w;
            accs[1][c] += a2.x * b.x + a2.y * b.y + a2.z * b.z + a2.w * b.w;
        }
    }
#pragma unroll
    for (int c = 0; c < 4; ++c) {
        int gc = colbase + ng + 16 * c;
        C[r1 * 128 + gc] = xc[r1 * 128 + gc] + accs[0][c];
        C[r2 * 128 + gc] = xc[r2 * 128 + gc] + accs[1][c];
    }
}

// ---------------------------------------------------------------------------
// lncomb: xn = x + LN1(y1) + LN2(y2). 8 rows/block, 32 lanes/row, f4 loads.
// ---------------------------------------------------------------------------
__global__ __launch_bounds__(256) void lncomb(const float* __restrict__ y1,
    const float* __restrict__ y2, const float* __restrict__ g1,
    const float* __restrict__ b1, const float* __restrict__ g2,
    const float* __restrict__ b2, const float* __restrict__ x,
    float* __restrict__ out)
{
    const int rl = threadIdx.x >> 5, lane = threadIdx.x & 31;
    const int row = blockIdx.x * 8 + rl;
    float4 v1 = *(const float4*)&y1[row * 128 + lane * 4];
    float4 v2 = *(const float4*)&y2[row * 128 + lane * 4];
    float4 xv = *(const float4*)&x[row * 128 + lane * 4];
    float4 ga = *(const float4*)&g1[lane * 4];
    float4 ba = *(const float4*)&b1[lane * 4];
    float4 gb = *(const float4*)&g2[lane * 4];
    float4 bb = *(const float4*)&b2[lane * 4];

    float s1 = v1.x + v1.y + v1.z + v1.w;
#pragma unroll
    for (int off = 16; off > 0; off >>= 1) s1 += __shfl_xor(s1, off);
    float mean1 = s1 * (1.0f / 128.0f);
    float d1x = v1.x - mean1, d1y = v1.y - mean1, d1z = v1.z - mean1, d1w = v1.w - mean1;
    float q1 = d1x * d1x + d1y * d1y + d1z * d1z + d1w * d1w;
#pragma unroll
    for (int off = 16; off > 0; off >>= 1) q1 += __shfl_xor(q1, off);
    float rs1 = rsqrtf(q1 * (1.0f / 128.0f) + 1e-5f);

    float s2 = v2.x + v2.y + v2.z + v2.w;
#pragma unroll
    for (int off = 16; off > 0; off >>= 1) s2 += __shfl_xor(s2, off);
    float mean2 = s2 * (1.0f / 128.0f);
    float d2x = v2.x - mean2, d2y = v2.y - mean2, d2z = v2.z - mean2, d2w = v2.w - mean2;
    float q2 = d2x * d2x + d2y * d2y + d2z * d2z + d2w * d2w;
#pragma unroll
    for (int off = 16; off > 0; off >>= 1) q2 += __shfl_xor(q2, off);
    float rs2 = rsqrtf(q2 * (1.0f / 128.0f) + 1e-5f);

    float4 o;
    o.x = xv.x + (d1x * rs1 * ga.x + ba.x) + (d2x * rs2 * gb.x + bb.x);
    o.y = xv.y + (d1y * rs1 * ga.y + ba.y) + (d2y * rs2 * gb.y + bb.y);
    o.z = xv.z + (d1z * rs1 * ga.z + ba.z) + (d2z * rs2 * gb.z + bb.z);
    o.w = xv.w + (d1w * rs1 * ga.w + ba.w) + (d2w * rs2 * gb.w + bb.w);
    *(float4*)&out[row * 128 + lane * 4] = o;
}

// ---------------------------------------------------------------------------
// linT: C[768x128] = A @ W^T + bias. Grid (24, 2). Same core as mega1.
// ---------------------------------------------------------------------------
__global__ __launch_bounds__(256) void linT(const float* __restrict__ A_,
    const float* __restrict__ W, const float* __restrict__ bias,
    float* __restrict__ C)
{
    __shared__ float Bs[64][132];
    const int colbase = blockIdx.y * 64;
    const int tid = threadIdx.x;
#pragma unroll
    for (int t = 0; t < 8; ++t) {
        int idx = tid + 256 * t;
        int row = idx >> 5, f4 = idx & 31;
        *(float4*)&Bs[row][f4 * 4] = *(const float4*)&W[(colbase + row) * 128 + f4 * 4];
    }
    __syncthreads();
    const int rg = tid >> 4, ng = tid & 15;
    const int r0 = blockIdx.x * 32;
    const int r1 = r0 + rg, r2 = r0 + rg + 16;
    float accs[2][4];
#pragma unroll
    for (int c = 0; c < 4; ++c) {
        float bv = bias[colbase + ng + 16 * c];
        accs[0][c] = bv; accs[1][c] = bv;
    }
    const float* A1 = A_ + r1 * 128;
    const float* A2 = A_ + r2 * 128;
#pragma unroll 8
    for (int kk = 0; kk < 32; ++kk) {
        float4 a1 = *(const float4*)&A1[kk * 4];
        float4 a2 = *(const float4*)&A2[kk * 4];
#pragma unroll
        for (int c = 0; c < 4; ++c) {
            float4 b = *(const float4*)&Bs[ng + 16 * c][kk * 4];
            accs[0][c] += a1.x * b.x + a1.y * b.y + a1.z * b.z + a1.w * b.w;
            accs[1][c] += a2.x * b.x + a2.y * b.y + a2.z * b.z + a2.w * b.w;
        }
    }
#pragma unroll
    for (int c = 0; c < 4; ++c) {
        int gc = colbase + ng + 16 * c;
        C[r1 * 128 + gc] = accs[0][c];
        C[r2 * 128 + gc] = accs[1][c];
    }
}

// ---------------------------------------------------------------------------
extern "C" void kernel_launch(void* const* d_in, const int* in_sizes, int n_in,
                              void* d_out, int out_size, void* d_ws, size_t ws_size,
                              hipStream_t stream)
{
    const float* x_in      = (const float*)d_in[0];
    const float* cop_l_w   = (const float*)d_in[1];
    const float* cop_l_b   = (const float*)d_in[2];
    const float* cop_lo_w  = (const float*)d_in[3];
    const float* cop_lo_b  = (const float*)d_in[4];
    const float* cop_out_w = (const float*)d_in[5];
    const float* cop_out_b = (const float*)d_in[6];
    const float* cop_ln_g  = (const float*)d_in[7];
    const float* cop_ln_b  = (const float*)d_in[8];
    const float* qkv_w     = (const float*)d_in[9];
    const float* qkv_b     = (const float*)d_in[10];
    const float* mha_out_w = (const float*)d_in[11];
    const float* mha_out_b = (const float*)d_in[12];
    const float* mha_ln_g  = (const float*)d_in[13];
    const float* mha_ln_b  = (const float*)d_in[14];
    const float* l1_w      = (const float*)d_in[15];
    const float* l1_b      = (const float*)d_in[16];

    float* ws = (float*)d_ws;
    float* xA    = ws + 0 * P_SZ;
    float* xB    = ws + 1 * P_SZ;
    float* a_    = ws + 2 * P_SZ;
    float* tx_   = ws + 3 * P_SZ;
    float* y1_   = ws + 4 * P_SZ;
    float* y2_   = ws + 5 * P_SZ;
    float* qkv_  = ws + 6 * P_SZ;           // 3*P_SZ floats
    float* o_    = ws + 9 * P_SZ;
    float* Mpart = ws + 10 * P_SZ;          // 16 * 16384 floats
    float* tspart= Mpart + 16 * 16384;      // 16 * 128

    const float* xc = x_in;
    float* xn = xA;

    for (int i = 0; i < 6; ++i) {
        const float* lw  = cop_l_w   + i * 16384;
        const float* lb  = cop_l_b   + i * 128;
        const float* low = cop_lo_w  + i * 16384;
        const float* lob = cop_lo_b  + i * 128;
        const float* ow  = cop_out_w + i * 16384;
        const float* ob  = cop_out_b + i * 128;
        const float* lg1 = cop_ln_g  + i * 128;
        const float* lb1 = cop_ln_b  + i * 128;
        const float* qw  = qkv_w     + i * 49152;
        const float* qb  = qkv_b     + i * 384;
        const float* mw  = mha_out_w + i * 16384;
        const float* mb  = mha_out_b + i * 128;
        const float* lg2 = mha_ln_g  + i * 128;
        const float* lb2 = mha_ln_b  + i * 128;

        mega1<<<dim3(24, 10), 256, 0, stream>>>(xc, lw, lb, ow, ob, qw, qb,
                                                a_, tx_, qkv_);
        k2<<<256, 256, 0, stream>>>(qkv_, a_, tx_, o_, Mpart, tspart);
        ygemm<<<dim3(24, 4), 256, 0, stream>>>(a_, o_, Mpart, low, lob, tspart,
                                               mw, mb, xc, y1_, y2_);
        lncomb<<<96, 256, 0, stream>>>(y1_, y2_, lg1, lb1, lg2, lb2, xc, xn);

        xc = xn;
        xn = (xc == xA) ? xB : xA;
    }

    linT<<<dim3(24, 2), 256, 0, stream>>>(xc, l1_w, l1_b, (float*)d_out);
}